// Round 5
// baseline (52.288 us; speedup 1.0000x reference)
//
#include <hip/hip_runtime.h>
#include <cmath>

constexpr int   DIM   = 2048;
constexpr int   NEXP  = 4;
constexpr float EPS   = 1e-6f;
constexpr float SCALE = 3.0f;

typedef float f32x4 __attribute__((ext_vector_type(4)));

// One wave per row, software-pipelined: while row r is being reduced, row
// r+1's 8 float4 loads are already in flight (double-buffered registers),
// so the wave always has ~8 KB outstanding -- including during the
// butterfly tail. Fused weights rw*nw stay register-resident (128 VGPR,
// R2 showed LDS weights serialize load issue). Each wave owns a CONTIGUOUS
// chunk of rows (128 KB sequential) for DRAM page locality.
// ~210 VGPR -> 2 waves/SIMD = 8 waves/CU.
__global__ __launch_bounds__(256, 2)
void altup_router_kernel(const float* __restrict__ x,
                         const float* __restrict__ nw,
                         const float* __restrict__ rw,
                         float* __restrict__ out,
                         int nrows, int chunk)
{
    const int tid  = threadIdx.x;
    const int lane = tid & 63;
    const int wid  = tid >> 6;
    const int wave = blockIdx.x * (blockDim.x >> 6) + wid;
    const int base = lane * 4;  // float offset inside each 256-float chunk

    // Preload fused weights: w[e][k] = rw[e*DIM + d] * nw[d]
    f32x4 w[NEXP][8];
#pragma unroll
    for (int e = 0; e < NEXP; ++e) {
#pragma unroll
        for (int k = 0; k < 8; ++k) {
            const int d = k * 256 + base;
            const f32x4 r = *reinterpret_cast<const f32x4*>(rw + e * DIM + d);
            const f32x4 n = *reinterpret_cast<const f32x4*>(nw + d);
            w[e][k] = r * n;
        }
    }

    int r    = wave * chunk;
    int rend = r + chunk;
    if (rend > nrows) rend = nrows;
    if (r >= rend) return;

    f32x4 bufA[8], bufB[8];

    auto LOAD = [&](f32x4 (&buf)[8], int row) {
        const float* xr = x + (size_t)row * DIM;
#pragma unroll
        for (int k = 0; k < 8; ++k)
            buf[k] = __builtin_nontemporal_load(
                         reinterpret_cast<const f32x4*>(xr + k * 256 + base));
    };

    auto PROC = [&](const f32x4 (&buf)[8], int row) {
        float acc[5] = {0.f, 0.f, 0.f, 0.f, 0.f};
#pragma unroll
        for (int k = 0; k < 8; ++k) {
            const f32x4 a = buf[k];
#pragma unroll
            for (int j = 0; j < 4; ++j)
                acc[0] = fmaf(a[j], a[j], acc[0]);
#pragma unroll
            for (int e = 0; e < NEXP; ++e) {
                const f32x4 we = w[e][k];
#pragma unroll
                for (int j = 0; j < 4; ++j)
                    acc[1 + e] = fmaf(a[j], we[j], acc[1 + e]);
            }
        }
#pragma unroll
        for (int m = 32; m >= 1; m >>= 1) {
#pragma unroll
            for (int i = 0; i < 5; ++i)
                acc[i] += __shfl_xor(acc[i], m, 64);
        }
        if (lane == 0) {
            const float ir = rsqrtf(acc[0] * (1.0f / DIM) + EPS);
            f32x4 o;
            o.x = tanhf(acc[1] * ir * SCALE);
            o.y = tanhf(acc[2] * ir * SCALE);
            o.z = tanhf(acc[3] * ir * SCALE);
            o.w = tanhf(acc[4] * ir * SCALE);
            *reinterpret_cast<f32x4*>(out + (size_t)row * 4) = o;
        }
    };

    LOAD(bufA, r);
    for (;;) {
        if (r + 1 < rend) LOAD(bufB, r + 1);   // prefetch BEFORE reduce
        PROC(bufA, r);
        ++r;
        if (r >= rend) break;
        if (r + 1 < rend) LOAD(bufA, r + 1);
        PROC(bufB, r);
        ++r;
        if (r >= rend) break;
    }
}

extern "C" void kernel_launch(void* const* d_in, const int* in_sizes, int n_in,
                              void* d_out, int out_size, void* d_ws, size_t ws_size,
                              hipStream_t stream)
{
    const float* x   = (const float*)d_in[0];  // (4, 8192, 2048) f32
    const float* nw  = (const float*)d_in[1];  // (2048,) f32
    const float* rw  = (const float*)d_in[2];  // (4, 2048) f32
    float*       out = (float*)d_out;          // (4, 8192, 4) f32

    const int nrows = in_sizes[0] / DIM;       // 32768

    // 512 blocks x 4 waves = 2048 waves = 8 waves/CU; each wave owns a
    // contiguous chunk of rows (16 rows = 128 KB for the full problem).
    int blocks = 512;
    int nwaves = blocks * 4;
    if (nwaves > nrows) {                      // tiny-input fallback
        nwaves = nrows;
        blocks = (nwaves + 3) / 4;
        if (blocks < 1) blocks = 1;
        nwaves = blocks * 4;
    }
    const int chunk = (nrows + nwaves - 1) / nwaves;

    hipLaunchKernelGGL(altup_router_kernel, dim3(blocks), dim3(256), 0, stream,
                       x, nw, rw, out, nrows, chunk);
}